// Round 7
// baseline (249.869 us; speedup 1.0000x reference)
//
#include <hip/hip_runtime.h>
#include <math.h>

typedef unsigned short u16;
typedef unsigned int   u32;
typedef __bf16 bf16_8 __attribute__((ext_vector_type(8)));
typedef float  f32x4  __attribute__((ext_vector_type(4)));

constexpr int CH   = 256;
constexpr int NPIX = 4096;

__device__ __forceinline__ u16 f2bf(float f) {
    u32 u = __float_as_uint(f);
    u = (u + 0x7FFFu + ((u >> 16) & 1u)) >> 16;
    return (u16)u;
}
__device__ __forceinline__ float bf2f(u16 h) { return __uint_as_float((u32)h << 16); }
__device__ __forceinline__ u32 encF(float f) {
    u32 u = __float_as_uint(f);
    return u ^ (u32)(((int)u >> 31) | 0x80000000);
}
__device__ __forceinline__ float decF(u32 u) {
    return __uint_as_float((u >> 31) ? (u ^ 0x80000000u) : ~u);
}

// ---------------------------------------------------------------------------
// Multi-job bf16 MFMA NT GEMM (modes 0 = bf16 store, 1 = split-K f32 atomics)
// ---------------------------------------------------------------------------
struct GJob {
    const u16* A; const u16* B;
    u16* outB; float* outF;
    const float* bias;
    long long sA, sB, sC;
    int lda, ldb, ldc, K, nSplit, mode, biasRow, gx, gy, nBlk;
};
struct GJobs { GJob j[4]; int n; };

template<int BM, int BN>
__global__ __launch_bounds__(256, 2)
void mfma_multi(GJobs jobs)
{
    constexpr int BK = 64;
    constexpr int MT = BM / 16;
    constexpr int WN = BN / 4;
    constexpr int NT = WN / 16;
    __shared__ __align__(16) u16 smem[BM * BK + BN * BK];
    u16* As = smem;
    u16* Bs = smem + BM * BK;
    u16* Ct = smem;   // epilogue reuse: BM*BN <= BM*BK + BN*BK for BK=64,BN<=128

    int ji = 0, start = 0;
    {
        int bxx = blockIdx.x;
        while (ji + 1 < jobs.n && bxx >= start + jobs.j[ji].nBlk) {
            start += jobs.j[ji].nBlk; ++ji;
        }
    }
    const GJob J = jobs.j[ji];
    const int local = blockIdx.x - start;
    const int per = J.gx * J.gy;
    const int bz = local / per;
    const int r2 = local - bz * per;
    const int by = r2 / J.gx;
    const int bx2 = r2 - by * J.gx;
    const int batch = bz / J.nSplit;
    const int split = bz - batch * J.nSplit;
    const int kLen = J.K / J.nSplit;
    const int kBeg = split * kLen;

    const u16* Ab = J.A + (size_t)batch * J.sA;
    const u16* Bb = J.B + (size_t)batch * J.sB;
    const int mBase = by * BM;
    const int nBase = bx2 * BN;
    const int tid = threadIdx.x;
    const int wave = tid >> 6, lane = tid & 63, lm = lane & 15, q = lane >> 4;

    f32x4 acc[MT][NT];
#pragma unroll
    for (int i = 0; i < MT; ++i)
#pragma unroll
        for (int j = 0; j < NT; ++j) acc[i][j] = f32x4{0.f, 0.f, 0.f, 0.f};

    const int srow = tid >> 3, sc8 = tid & 7;

    for (int k0 = kBeg; k0 < kBeg + kLen; k0 += BK) {
        __syncthreads();
#pragma unroll
        for (int it = 0; it < BM / 32; ++it) {
            int r = srow + it * 32;
            uint4 v = *(const uint4*)(Ab + (size_t)(mBase + r) * J.lda + k0 + sc8 * 8);
            *(uint4*)&As[r * BK + ((sc8 ^ (r & 7)) * 8)] = v;
        }
#pragma unroll
        for (int it = 0; it < BN / 32; ++it) {
            int r = srow + it * 32;
            uint4 v = *(const uint4*)(Bb + (size_t)(nBase + r) * J.ldb + k0 + sc8 * 8);
            *(uint4*)&Bs[r * BK + ((sc8 ^ (r & 7)) * 8)] = v;
        }
        __syncthreads();
#pragma unroll
        for (int ks = 0; ks < 2; ++ks) {
            bf16_8 af[MT], bfr[NT];
#pragma unroll
            for (int mt = 0; mt < MT; ++mt) {
                int r = mt * 16 + lm;
                af[mt] = *(const bf16_8*)&As[r * BK + (((ks * 4 + q) ^ (lm & 7)) * 8)];
            }
#pragma unroll
            for (int nt = 0; nt < NT; ++nt) {
                int r = wave * WN + nt * 16 + lm;
                bfr[nt] = *(const bf16_8*)&Bs[r * BK + (((ks * 4 + q) ^ (lm & 7)) * 8)];
            }
#pragma unroll
            for (int mt = 0; mt < MT; ++mt)
#pragma unroll
                for (int nt = 0; nt < NT; ++nt)
                    acc[mt][nt] = __builtin_amdgcn_mfma_f32_16x16x32_bf16(
                        af[mt], bfr[nt], acc[mt][nt], 0, 0, 0);
        }
    }

    if (J.mode == 1) {
#pragma unroll
        for (int nt = 0; nt < NT; ++nt) {
            int col = nBase + wave * WN + nt * 16 + lm;
#pragma unroll
            for (int mt = 0; mt < MT; ++mt)
#pragma unroll
                for (int r = 0; r < 4; ++r) {
                    int row = mBase + mt * 16 + q * 4 + r;
                    atomicAdd(&J.outF[(size_t)batch * J.sC + (size_t)row * J.ldc + col],
                              acc[mt][nt][r]);
                }
        }
        return;
    }

    __syncthreads();
#pragma unroll
    for (int nt = 0; nt < NT; ++nt) {
        int lc = wave * WN + nt * 16 + lm;
#pragma unroll
        for (int mt = 0; mt < MT; ++mt)
#pragma unroll
            for (int r = 0; r < 4; ++r)
                Ct[(mt * 16 + q * 4 + r) * BN + lc] = f2bf(acc[mt][nt][r]);
    }
    __syncthreads();

    constexpr int CPR = BN / 8;
    constexpr int RSTEP = 256 / CPR;
    constexpr int PT = BM / RSTEP;
    const int cc = (tid % CPR) * 8;
    const int lr0 = tid / CPR;

    float cbv[8];
    if (J.bias && !J.biasRow) {
#pragma unroll
        for (int j = 0; j < 8; ++j) cbv[j] = J.bias[nBase + cc + j];
    } else {
#pragma unroll
        for (int j = 0; j < 8; ++j) cbv[j] = 0.f;
    }

#pragma unroll
    for (int i = 0; i < PT; ++i) {
        int lr = lr0 + i * RSTEP;
        int R = mBase + lr;
        uint4 raw = *(const uint4*)&Ct[lr * BN + cc];
        u32 w[4] = {raw.x, raw.y, raw.z, raw.w};
        float rb = (J.bias && J.biasRow) ? J.bias[R] : 0.f;
        u32 o[4];
#pragma unroll
        for (int jj = 0; jj < 4; ++jj) {
            u16 lo = f2bf(bf2f((u16)(w[jj] & 0xFFFFu)) + cbv[2 * jj] + rb);
            u16 hi = f2bf(bf2f((u16)(w[jj] >> 16)) + cbv[2 * jj + 1] + rb);
            o[jj] = (u32)lo | ((u32)hi << 16);
        }
        *(uint4*)&J.outB[(size_t)batch * J.sC + (size_t)R * J.ldc + nBase + cc] =
            make_uint4(o[0], o[1], o[2], o[3]);
    }
}

// ---------------------------------------------------------------------------
// Y3: yT = gT x att ; z_cnl = BN(yT x W_z)+x ; t2 = z x W_t2 -> T2f
// ---------------------------------------------------------------------------
__global__ __launch_bounds__(256, 2)
void y3(const u16* __restrict__ gT, const float* __restrict__ attF,
        const u16* __restrict__ w_z, const u16* __restrict__ xTb,
        const u16* __restrict__ w_t2,
        u16* __restrict__ zb, u16* __restrict__ T2f,
        const float* __restrict__ bias, const float* __restrict__ bng,
        const float* __restrict__ bnb, const float* __restrict__ bnm,
        const float* __restrict__ bnv, const float* __restrict__ bias2)
{
    __shared__ __align__(16) u16 smem[40960];
    u16* sAtt = smem;          // [2][128][64] swz; later zt [4][64][64] swz
    u16* yA   = smem + 16384;  // As [64][64] swz; later yt [2][64][64] swz
    u16* Bs   = smem + 24576;  // [256][64] swz; later w_t2 [4][64][64] swz

    const int bz = blockIdx.z, mBase = blockIdx.y * 64;
    const int tid = threadIdx.x;
    const int wave = tid >> 6, lane = tid & 63, lm = lane & 15, q = lane >> 4;
    const int srow = tid >> 3, sc8 = tid & 7;

    {
        const float* src = attF + (size_t)bz * 16384;
#pragma unroll
        for (int i = 0; i < 8; ++i) {
            int id = tid + i * 256;
            int r = id >> 4, cg = id & 15;
            int kc = cg >> 3, c8 = cg & 7;
            const float* s = src + r * 128 + kc * 64 + c8 * 8;
            u32 o[4];
#pragma unroll
            for (int j = 0; j < 4; ++j) {
                u16 lo = f2bf(s[2 * j] * (1.f / 128.f));
                u16 hi = f2bf(s[2 * j + 1] * (1.f / 128.f));
                o[j] = (u32)lo | ((u32)hi << 16);
            }
            *(uint4*)&sAtt[kc * 8192 + r * 64 + ((c8 ^ (r & 7)) * 8)] =
                make_uint4(o[0], o[1], o[2], o[3]);
        }
    }

    f32x4 acc1[4][2];
#pragma unroll
    for (int i = 0; i < 4; ++i)
#pragma unroll
        for (int j = 0; j < 2; ++j) acc1[i][j] = f32x4{0.f, 0.f, 0.f, 0.f};
    for (int kc = 0; kc < 2; ++kc) {
        __syncthreads();
#pragma unroll
        for (int it = 0; it < 2; ++it) {
            int r = srow + it * 32;
            uint4 v = *(const uint4*)(gT + (size_t)bz * 524288 +
                                      (size_t)(mBase + r) * 128 + kc * 64 + sc8 * 8);
            *(uint4*)&yA[r * 64 + ((sc8 ^ (r & 7)) * 8)] = v;
        }
        __syncthreads();
#pragma unroll
        for (int ks = 0; ks < 2; ++ks) {
            bf16_8 af[4], bfr[2];
#pragma unroll
            for (int mt = 0; mt < 4; ++mt) {
                int m = mt * 16 + lm;
                af[mt] = *(const bf16_8*)&yA[m * 64 + (((ks * 4 + q) ^ (m & 7)) * 8)];
            }
#pragma unroll
            for (int nt = 0; nt < 2; ++nt) {
                int rb = wave * 32 + nt * 16 + lm;
                bfr[nt] = *(const bf16_8*)&sAtt[kc * 8192 + rb * 64 +
                                                (((ks * 4 + q) ^ (rb & 7)) * 8)];
            }
#pragma unroll
            for (int mt = 0; mt < 4; ++mt)
#pragma unroll
                for (int nt = 0; nt < 2; ++nt)
                    acc1[mt][nt] = __builtin_amdgcn_mfma_f32_16x16x32_bf16(
                        af[mt], bfr[nt], acc1[mt][nt], 0, 0, 0);
        }
    }
    __syncthreads();
#pragma unroll
    for (int nt = 0; nt < 2; ++nt) {
        int pcol = wave * 32 + nt * 16 + lm;
        int kc = pcol >> 6, c = pcol & 63;
#pragma unroll
        for (int mt = 0; mt < 4; ++mt)
#pragma unroll
            for (int r = 0; r < 4; ++r) {
                int prow = mt * 16 + q * 4 + r;
                yA[kc * 4096 + prow * 64 + (((c >> 3) ^ (prow & 7)) * 8) + (c & 7)] =
                    f2bf(acc1[mt][nt][r]);
            }
    }

    f32x4 acc2[4][4];
#pragma unroll
    for (int i = 0; i < 4; ++i)
#pragma unroll
        for (int j = 0; j < 4; ++j) acc2[i][j] = f32x4{0.f, 0.f, 0.f, 0.f};
    for (int kc = 0; kc < 2; ++kc) {
        __syncthreads();
#pragma unroll
        for (int it = 0; it < 8; ++it) {
            int r = srow + it * 32;
            uint4 v = *(const uint4*)(w_z + (size_t)r * 128 + kc * 64 + sc8 * 8);
            *(uint4*)&Bs[r * 64 + ((sc8 ^ (r & 7)) * 8)] = v;
        }
        __syncthreads();
#pragma unroll
        for (int ks = 0; ks < 2; ++ks) {
            bf16_8 af[4], bfr[4];
#pragma unroll
            for (int mt = 0; mt < 4; ++mt) {
                int m = mt * 16 + lm;
                af[mt] = *(const bf16_8*)&yA[kc * 4096 + m * 64 +
                                             (((ks * 4 + q) ^ (m & 7)) * 8)];
            }
#pragma unroll
            for (int nt = 0; nt < 4; ++nt) {
                int rb = wave * 64 + nt * 16 + lm;
                bfr[nt] = *(const bf16_8*)&Bs[rb * 64 + (((ks * 4 + q) ^ (rb & 7)) * 8)];
            }
#pragma unroll
            for (int mt = 0; mt < 4; ++mt)
#pragma unroll
                for (int nt = 0; nt < 4; ++nt)
                    acc2[mt][nt] = __builtin_amdgcn_mfma_f32_16x16x32_bf16(
                        af[mt], bfr[nt], acc2[mt][nt], 0, 0, 0);
        }
    }
#pragma unroll
    for (int nt = 0; nt < 4; ++nt) {
        int pcol = wave * 64 + nt * 16 + lm;
        int kc = pcol >> 6, c = pcol & 63;
#pragma unroll
        for (int mt = 0; mt < 4; ++mt)
#pragma unroll
            for (int r = 0; r < 4; ++r) {
                int prow = mt * 16 + q * 4 + r;
                sAtt[kc * 4096 + prow * 64 + (((c >> 3) ^ (prow & 7)) * 8) + (c & 7)] =
                    f2bf(acc2[mt][nt][r]);
            }
    }
    __syncthreads();

    {
        const int cc = (tid & 31) * 8, lr0 = tid >> 5;
        float csc[8], csh[8], cbv[8];
#pragma unroll
        for (int j = 0; j < 8; ++j) {
            int C = cc + j;
            float sc = bng[C] * rsqrtf(bnv[C] + 1e-5f);
            csc[j] = sc;
            csh[j] = bnb[C] - bnm[C] * sc;
            cbv[j] = bias[C];
        }
        int kcz = cc >> 6, c8z = (cc & 63) >> 3;
#pragma unroll
        for (int i = 0; i < 8; ++i) {
            int lr = lr0 + i * 8;
            int R = mBase + lr;
            int a = kcz * 4096 + lr * 64 + ((c8z ^ (lr & 7)) * 8);
            uint4 raw = *(const uint4*)&sAtt[a];
            u32 w[4] = {raw.x, raw.y, raw.z, raw.w};
            uint4 rr = *(const uint4*)&xTb[(size_t)bz * 1048576 + (size_t)R * 256 + cc];
            u32 rw[4] = {rr.x, rr.y, rr.z, rr.w};
            u32 o[4];
#pragma unroll
            for (int jj = 0; jj < 4; ++jj) {
                float z0 = (bf2f((u16)(w[jj] & 0xFFFFu)) + cbv[2 * jj]) * csc[2 * jj] +
                           csh[2 * jj] + bf2f((u16)(rw[jj] & 0xFFFFu));
                float z1 = (bf2f((u16)(w[jj] >> 16)) + cbv[2 * jj + 1]) * csc[2 * jj + 1] +
                           csh[2 * jj + 1] + bf2f((u16)(rw[jj] >> 16));
                o[jj] = (u32)f2bf(z0) | ((u32)f2bf(z1) << 16);
            }
            *(uint4*)&zb[(size_t)bz * 1048576 + (size_t)R * 256 + cc] =
                make_uint4(o[0], o[1], o[2], o[3]);
            *(uint4*)&sAtt[a] = make_uint4(o[0], o[1], o[2], o[3]);
        }
    }
#pragma unroll
    for (int i = 0; i < 8; ++i) {
        int id = tid + i * 256;
        int r = id >> 5, cg = id & 31;
        int kc = cg >> 3, c8 = cg & 7;
        uint4 v = *(const uint4*)(w_t2 + r * 256 + kc * 64 + c8 * 8);
        *(uint4*)&Bs[kc * 4096 + r * 64 + ((c8 ^ (r & 7)) * 8)] = v;
    }
    __syncthreads();

    f32x4 acc3[4];
#pragma unroll
    for (int i = 0; i < 4; ++i) acc3[i] = f32x4{0.f, 0.f, 0.f, 0.f};
#pragma unroll
    for (int kc = 0; kc < 4; ++kc)
#pragma unroll
        for (int ks = 0; ks < 2; ++ks) {
            int rb = wave * 16 + lm;
            bf16_8 bf = *(const bf16_8*)&Bs[kc * 4096 + rb * 64 +
                                            (((ks * 4 + q) ^ (rb & 7)) * 8)];
#pragma unroll
            for (int mt = 0; mt < 4; ++mt) {
                int m = mt * 16 + lm;
                bf16_8 af = *(const bf16_8*)&sAtt[kc * 4096 + m * 64 +
                                                  (((ks * 4 + q) ^ (m & 7)) * 8)];
                acc3[mt] = __builtin_amdgcn_mfma_f32_16x16x32_bf16(af, bf, acc3[mt], 0, 0, 0);
            }
        }
    const int d = wave * 16 + lm;
    const float b2 = bias2[d];
#pragma unroll
    for (int mt = 0; mt < 4; ++mt)
#pragma unroll
        for (int r = 0; r < 4; ++r) {
            int pix = mBase + mt * 16 + q * 4 + r;
            T2f[(size_t)bz * 262144 + (size_t)(pix & 2047) * 128 + (pix >> 11) * 64 + d] =
                f2bf(acc3[mt][r] + b2);
        }
}

// ---------------------------------------------------------------------------
// P3: Y = T2f x S (unfold) ; z_pnl = BN(Y x W_zp)+z (in place) + mean/max
// ---------------------------------------------------------------------------
__global__ __launch_bounds__(256, 2)
void p3(const u16* __restrict__ T2f, const float* __restrict__ SF,
        const u16* __restrict__ w_zp, u16* __restrict__ zb,
        float* __restrict__ meanS, u32* __restrict__ maxU,
        const float* __restrict__ bias, const float* __restrict__ bng,
        const float* __restrict__ bnb, const float* __restrict__ bnm,
        const float* __restrict__ bnv)
{
    __shared__ __align__(16) u16 smem[26624];
    u16* sS = smem;
    u16* yA = smem + 16896;
    float* sSum = (float*)&smem[25600];
    u32*   sMax = (u32*)&smem[26112];

    const int bz = blockIdx.z, mBase2 = blockIdx.y * 64;
    const int tid = threadIdx.x;
    const int wave = tid >> 6, lane = tid & 63, lm = lane & 15, q = lane >> 4;
    const int srow = tid >> 3, sc8 = tid & 7;

    {
        const float* src = SF + (size_t)bz * 16384;
#pragma unroll
        for (int i = 0; i < 8; ++i) {
            int id = tid + i * 256;
            int r = id >> 4, cg = id & 15;
            int kc = cg >> 3, c8 = cg & 7;
            int k0 = kc * 64 + c8 * 8;
            u32 o[4];
#pragma unroll
            for (int j = 0; j < 4; ++j) {
                int ka = k0 + 2 * j, kb = ka + 1;
                float va = src[r * 128 + 2 * (ka & 63) + (ka >> 6)] * (1.f / 2048.f);
                float vb = src[r * 128 + 2 * (kb & 63) + (kb >> 6)] * (1.f / 2048.f);
                o[j] = (u32)f2bf(va) | ((u32)f2bf(vb) << 16);
            }
            *(uint4*)&sS[kc * 8192 + r * 64 + ((c8 ^ (r & 7)) * 8)] =
                make_uint4(o[0], o[1], o[2], o[3]);
        }
    }

    f32x4 acc1[4][2];
#pragma unroll
    for (int i = 0; i < 4; ++i)
#pragma unroll
        for (int j = 0; j < 2; ++j) acc1[i][j] = f32x4{0.f, 0.f, 0.f, 0.f};
    for (int kc = 0; kc < 2; ++kc) {
        __syncthreads();
#pragma unroll
        for (int it = 0; it < 2; ++it) {
            int r = srow + it * 32;
            uint4 v = *(const uint4*)(T2f + (size_t)bz * 262144 +
                                      (size_t)(mBase2 + r) * 128 + kc * 64 + sc8 * 8);
            *(uint4*)&yA[r * 64 + ((sc8 ^ (r & 7)) * 8)] = v;
        }
        __syncthreads();
#pragma unroll
        for (int ks = 0; ks < 2; ++ks) {
            bf16_8 af[4], bfr[2];
#pragma unroll
            for (int mt = 0; mt < 4; ++mt) {
                int m = mt * 16 + lm;
                af[mt] = *(const bf16_8*)&yA[m * 64 + (((ks * 4 + q) ^ (m & 7)) * 8)];
            }
#pragma unroll
            for (int nt = 0; nt < 2; ++nt) {
                int rb = wave * 32 + nt * 16 + lm;
                bfr[nt] = *(const bf16_8*)&sS[kc * 8192 + rb * 64 +
                                              (((ks * 4 + q) ^ (rb & 7)) * 8)];
            }
#pragma unroll
            for (int mt = 0; mt < 4; ++mt)
#pragma unroll
                for (int nt = 0; nt < 2; ++nt)
                    acc1[mt][nt] = __builtin_amdgcn_mfma_f32_16x16x32_bf16(
                        af[mt], bfr[nt], acc1[mt][nt], 0, 0, 0);
        }
    }
    __syncthreads();
#pragma unroll
    for (int nt = 0; nt < 2; ++nt) {
        int pcol = wave * 32 + nt * 16 + lm;
        int half = pcol & 1, ch = pcol >> 1;
#pragma unroll
        for (int mt = 0; mt < 4; ++mt)
#pragma unroll
            for (int r = 0; r < 4; ++r) {
                int prow = mt * 16 + q * 4 + r;
                yA[(half * 64 + prow) * 68 + ch] = f2bf(acc1[mt][nt][r]);
            }
    }
#pragma unroll
    for (int it = 0; it < 8; ++it) {
        int r = srow + it * 32;
        uint4 v = *(const uint4*)(w_zp + (size_t)r * 64 + sc8 * 8);
        *(uint4*)&sS[r * 64 + ((sc8 ^ (r & 7)) * 8)] = v;
    }
    __syncthreads();

    f32x4 acc2[8][4];
#pragma unroll
    for (int i = 0; i < 8; ++i)
#pragma unroll
        for (int j = 0; j < 4; ++j) acc2[i][j] = f32x4{0.f, 0.f, 0.f, 0.f};
#pragma unroll
    for (int ks = 0; ks < 2; ++ks) {
        bf16_8 bfr[4];
#pragma unroll
        for (int nt = 0; nt < 4; ++nt) {
            int rb = wave * 64 + nt * 16 + lm;
            bfr[nt] = *(const bf16_8*)&sS[rb * 64 + (((ks * 4 + q) ^ (rb & 7)) * 8)];
        }
#pragma unroll
        for (int mt = 0; mt < 8; ++mt) {
            int m = mt * 16 + lm;
            bf16_8 af = *(const bf16_8*)&yA[m * 68 + ks * 32 + q * 8];
#pragma unroll
            for (int nt = 0; nt < 4; ++nt)
                acc2[mt][nt] = __builtin_amdgcn_mfma_f32_16x16x32_bf16(
                    af, bfr[nt], acc2[mt][nt], 0, 0, 0);
        }
    }

    const int cc = (tid & 31) * 8, lr0 = tid >> 5;
    float csc[8], csh[8], cbv[8], tsum[8], tmax[8];
#pragma unroll
    for (int j = 0; j < 8; ++j) {
        int C = cc + j;
        float sc = bng[C] * rsqrtf(bnv[C] + 1e-5f);
        csc[j] = sc;
        csh[j] = bnb[C] - bnm[C] * sc;
        cbv[j] = bias[C];
        tsum[j] = 0.f; tmax[j] = -1e30f;
    }
#pragma unroll
    for (int h = 0; h < 2; ++h) {
        __syncthreads();
#pragma unroll
        for (int nt = 0; nt < 4; ++nt) {
            int pcol = wave * 64 + nt * 16 + lm;
#pragma unroll
            for (int mt = 0; mt < 4; ++mt)
#pragma unroll
                for (int r = 0; r < 4; ++r) {
                    int prow = mt * 16 + q * 4 + r;
                    sS[prow * 264 + pcol] = f2bf(acc2[h * 4 + mt][nt][r]);
                }
        }
        __syncthreads();
#pragma unroll
        for (int i = 0; i < 8; ++i) {
            int lr = lr0 + i * 8;
            int pix = h * 2048 + mBase2 + lr;
            uint4 raw = *(const uint4*)&sS[lr * 264 + cc];
            u32 w[4] = {raw.x, raw.y, raw.z, raw.w};
            size_t off = (size_t)bz * 1048576 + (size_t)pix * 256 + cc;
            uint4 rr = *(const uint4*)&zb[off];
            u32 rw[4] = {rr.x, rr.y, rr.z, rr.w};
            u32 o[4];
#pragma unroll
            for (int jj = 0; jj < 4; ++jj) {
                float z0 = (bf2f((u16)(w[jj] & 0xFFFFu)) + cbv[2 * jj]) * csc[2 * jj] +
                           csh[2 * jj] + bf2f((u16)(rw[jj] & 0xFFFFu));
                float z1 = (bf2f((u16)(w[jj] >> 16)) + cbv[2 * jj + 1]) * csc[2 * jj + 1] +
                           csh[2 * jj + 1] + bf2f((u16)(rw[jj] >> 16));
                u16 lo = f2bf(z0), hi = f2bf(z1);
                o[jj] = (u32)lo | ((u32)hi << 16);
                tsum[2 * jj] += bf2f(lo); tsum[2 * jj + 1] += bf2f(hi);
                tmax[2 * jj] = fmaxf(tmax[2 * jj], bf2f(lo));
                tmax[2 * jj + 1] = fmaxf(tmax[2 * jj + 1], bf2f(hi));
            }
            *(uint4*)&zb[off] = make_uint4(o[0], o[1], o[2], o[3]);
        }
    }
    __syncthreads();
    sSum[tid] = 0.f; sMax[tid] = 0u;
    __syncthreads();
#pragma unroll
    for (int j = 0; j < 8; ++j) {
        atomicAdd(&sSum[cc + j], tsum[j]);
        atomicMax(&sMax[cc + j], encF(tmax[j]));
    }
    __syncthreads();
    atomicAdd(&meanS[bz * CH + tid], sSum[tid]);
    atomicMax(&maxU[bz * CH + tid], sMax[tid]);
}

// ---------------------------------------------------------------------------
// prep + transpose-cast with vectorized uint4 stores
// ---------------------------------------------------------------------------
__global__ __launch_bounds__(256)
void prep_tcast(const float* __restrict__ x, u16* __restrict__ xTb,
                const float* __restrict__ x0, u16* __restrict__ x0Tb,
                const float* w0, const float* w1, const float* w2, const float* w3,
                const float* w4, const float* w5, const float* w6, const float* w7,
                const float* pgb, const float* ppb,
                float* __restrict__ zr, u16* __restrict__ wsb, float* __restrict__ pb128)
{
    __shared__ u16 T[64][68];
    const int bx = blockIdx.x, tid = threadIdx.x;
    if (bx < 3072) {
        const int b = bx / 384, rem = bx % 384;
        const int by = rem / 64, nb = (rem % 64) * 64;
        const bool isX = by < 4;
        const int C = isX ? 256 : 128;
        const float* in = isX ? x : x0;
        u16* outp = isX ? xTb : x0Tb;
        const int cb = (isX ? by : by - 4) * 64;
        {
            int nl = tid & 63, cq = tid >> 6;
#pragma unroll
            for (int i = 0; i < 16; ++i) {
                int c = cq * 16 + i;
                T[c][nl] = f2bf(in[(size_t)b * C * NPIX + (size_t)(cb + c) * NPIX + nb + nl]);
            }
        }
        __syncthreads();
        {
            int g = tid & 7, n0 = tid >> 3;   // 8 ch-groups x 32 rows
#pragma unroll
            for (int i = 0; i < 2; ++i) {
                int n = n0 + i * 32;
                u32 o[4];
#pragma unroll
                for (int j = 0; j < 4; ++j) {
                    int c = g * 8 + 2 * j;
                    o[j] = (u32)T[c][n] | ((u32)T[c + 1][n] << 16);
                }
                *(uint4*)&outp[((size_t)b * NPIX + nb + n) * C + cb + g * 8] =
                    make_uint4(o[0], o[1], o[2], o[3]);
            }
        }
    } else {
        int i = (bx - 3072) * 256 + tid;
        if (i < 266240) zr[i] = 0.f;
        int j = i - 266240;
        if (j >= 0 && j < 147456) {
            float v;
            if      (j < 32768)  v = w0[j];
            else if (j < 49152)  v = w1[j - 32768];
            else if (j < 65536)  v = w2[j - 49152];
            else if (j < 98304)  v = w3[j - 65536];
            else if (j < 106496) v = w4[j - 98304];
            else if (j < 114688) v = w5[j - 106496];
            else if (j < 131072) v = w6[j - 114688];
            else                 v = w7[j - 131072];
            wsb[j] = f2bf(v);
        }
        int k = i - 413696;
        if (k >= 0 && k < 128) pb128[k] = (k < 64) ? pgb[k] : ppb[k - 64];
    }
}

__global__ __launch_bounds__(256)
void sa_ca(const u16* __restrict__ z, const float* __restrict__ meanS,
           const u32* __restrict__ maxU, const float* __restrict__ fc1,
           const float* __restrict__ fc2, float* __restrict__ ca,
           float* __restrict__ sain)
{
    const int b = blockIdx.y, tid = threadIdx.x;
    __shared__ float s_avg[CH], s_mx[CH], s_h[16], s_ca[CH];
    s_avg[tid] = meanS[b * CH + tid] * (1.f / NPIX);
    s_mx[tid]  = decF(maxU[b * CH + tid]);
    __syncthreads();
    if (tid < 16) {
        float ha = 0.f, hm = 0.f;
        for (int c = 0; c < CH; ++c) {
            float w = fc1[tid * CH + c];
            ha += w * s_avg[c];
            hm += w * s_mx[c];
        }
        s_h[tid] = fmaxf(ha, 0.f) + fmaxf(hm, 0.f);
    }
    __syncthreads();
    float o = 0.f;
#pragma unroll
    for (int h = 0; h < 16; ++h) o += fc2[tid * 16 + h] * s_h[h];
    float cav = 1.f / (1.f + expf(-o));
    s_ca[tid] = cav;
    if (blockIdx.x == 0) ca[b * CH + tid] = cav;
    __syncthreads();

    const int p = tid >> 2, part = tid & 3;
    const int n = blockIdx.x * 64 + p;
    const uint4* zr = (const uint4*)(z + ((size_t)b * NPIX + n) * CH + part * 64);
    float s = 0.f, m = -1e30f;
#pragma unroll
    for (int i = 0; i < 8; ++i) {
        uint4 v = zr[i];
        u32 w[4] = {v.x, v.y, v.z, v.w};
#pragma unroll
        for (int j = 0; j < 4; ++j) {
            int c = part * 64 + i * 8 + j * 2;
            float a = bf2f((u16)(w[j] & 0xFFFFu)) * s_ca[c];
            float d = bf2f((u16)(w[j] >> 16)) * s_ca[c + 1];
            s += a + d;
            m = fmaxf(m, fmaxf(a, d));
        }
    }
    s += __shfl_xor(s, 1); s += __shfl_xor(s, 2);
    m = fmaxf(m, __shfl_xor(m, 1)); m = fmaxf(m, __shfl_xor(m, 2));
    if (part == 0) {
        sain[(size_t)b * 2 * NPIX + n] = s * (1.f / CH);
        sain[(size_t)b * 2 * NPIX + NPIX + n] = m;
    }
}

// fused: 7x7 conv + sigmoid + weighted fusion, vectorized loads/stores
__global__ __launch_bounds__(256)
void fuse_conv(const u16* __restrict__ z, const float* __restrict__ ca,
               const float* __restrict__ sain, const float* __restrict__ sa_w,
               const float* __restrict__ x, const float* __restrict__ fwp,
               float* __restrict__ out)
{
    __shared__ float ws[98];
    __shared__ float s_sig[64];
    __shared__ float s_ca2[64];
    __shared__ float T[64][65];
    const int b = blockIdx.z, cb = blockIdx.y * 64, h = blockIdx.x;
    const int nb = h * 64;
    const int tid = threadIdx.x;
    if (tid < 98) ws[tid] = sa_w[tid];
    if (tid >= 128 && tid < 192) s_ca2[tid - 128] = ca[b * CH + cb + (tid - 128)];
    __syncthreads();
    if (tid < 64) {
        const float* p = sain + (size_t)b * 2 * NPIX;
        float s = 0.f;
#pragma unroll
        for (int ky = 0; ky < 7; ++ky) {
            int yy = h + ky - 3;
            if (yy < 0 || yy >= 64) continue;
#pragma unroll
            for (int kx = 0; kx < 7; ++kx) {
                int xx = tid + kx - 3;
                if (xx < 0 || xx >= 64) continue;
                s += ws[ky * 7 + kx] * p[yy * 64 + xx] +
                     ws[49 + ky * 7 + kx] * p[NPIX + yy * 64 + xx];
            }
        }
        s_sig[tid] = 1.f / (1.f + expf(-s));
    }
    __syncthreads();
    {
        int g = tid & 7, n0 = tid >> 3;
#pragma unroll
        for (int i = 0; i < 2; ++i) {
            int n = n0 + i * 32;
            uint4 v = *(const uint4*)&z[((size_t)b * NPIX + nb + n) * CH + cb + g * 8];
            u32 w[4] = {v.x, v.y, v.z, v.w};
            float sg = s_sig[n];
#pragma unroll
            for (int j = 0; j < 4; ++j) {
                int c = g * 8 + 2 * j;
                T[c][n]     = bf2f((u16)(w[j] & 0xFFFFu)) * s_ca2[c] * sg;
                T[c + 1][n] = bf2f((u16)(w[j] >> 16)) * s_ca2[c + 1] * sg;
            }
        }
    }
    __syncthreads();
    const float fw = fwp[0];
    {
        int qn = tid & 15, c0 = tid >> 4;
#pragma unroll
        for (int i = 0; i < 4; ++i) {
            int c = c0 + i * 16;
            size_t o = ((size_t)b * CH + cb + c) * NPIX + nb + qn * 4;
            float4 xv = *(const float4*)&x[o];
            float4 ov;
            ov.x = fw * T[c][qn * 4 + 0] + (1.f - fw) * xv.x;
            ov.y = fw * T[c][qn * 4 + 1] + (1.f - fw) * xv.y;
            ov.z = fw * T[c][qn * 4 + 2] + (1.f - fw) * xv.z;
            ov.w = fw * T[c][qn * 4 + 3] + (1.f - fw) * xv.w;
            *(float4*)&out[o] = ov;
        }
    }
}

static GJob mkjob(const u16* A, const u16* B, u16* outB, float* outF,
                  const float* bias,
                  long long sA, long long sB, long long sC,
                  int lda, int ldb, int ldc, int K, int nSplit, int mode,
                  int biasRow, int gx, int gy)
{
    GJob g;
    g.A = A; g.B = B; g.outB = outB; g.outF = outF; g.bias = bias;
    g.sA = sA; g.sB = sB; g.sC = sC;
    g.lda = lda; g.ldb = ldb; g.ldc = ldc; g.K = K; g.nSplit = nSplit;
    g.mode = mode; g.biasRow = biasRow; g.gx = gx; g.gy = gy;
    g.nBlk = gx * gy * 8 * nSplit;
    return g;
}

extern "C" void kernel_launch(void* const* d_in, const int* in_sizes, int n_in,
                              void* d_out, int out_size, void* d_ws, size_t ws_size,
                              hipStream_t stream)
{
    const float* x        = (const float*)d_in[0];
    const float* x0       = (const float*)d_in[1];
    const float* cnl_g_w  = (const float*)d_in[2];
    const float* cnl_g_b  = (const float*)d_in[3];
    const float* cnl_th_w = (const float*)d_in[4];
    const float* cnl_th_b = (const float*)d_in[5];
    const float* cnl_ph_w = (const float*)d_in[6];
    const float* cnl_ph_b = (const float*)d_in[7];
    const float* cnl_W_w  = (const float*)d_in[8];
    const float* cnl_W_b  = (const float*)d_in[9];
    const float* cnl_bn_g = (const float*)d_in[10];
    const float* cnl_bn_b = (const float*)d_in[11];
    const float* cnl_bn_m = (const float*)d_in[12];
    const float* cnl_bn_v = (const float*)d_in[13];
    const float* pnl_g_w  = (const float*)d_in[14];
    const float* pnl_g_b  = (const float*)d_in[15];
    const float* pnl_th_w = (const float*)d_in[16];
    const float* pnl_th_b = (const float*)d_in[17];
    const float* pnl_ph_w = (const float*)d_in[18];
    const float* pnl_ph_b = (const float*)d_in[19];
    const float* pnl_W_w  = (const float*)d_in[20];
    const float* pnl_W_b  = (const float*)d_in[21];
    const float* pnl_bn_g = (const float*)d_in[22];
    const float* pnl_bn_b = (const float*)d_in[23];
    const float* pnl_bn_m = (const float*)d_in[24];
    const float* pnl_bn_v = (const float*)d_in[25];
    const float* ca_fc1   = (const float*)d_in[26];
    const float* ca_fc2   = (const float*)d_in[27];
    const float* sa_w     = (const float*)d_in[28];
    const float* fw       = (const float*)d_in[29];
    float* out = (float*)d_out;
    char* wsc  = (char*)d_ws;

    u16* xTb   = (u16*)(wsc + 0);            // [8][4096][256]
    u16* x0Tb  = (u16*)(wsc + 16777216);     // [8][4096][128]
    u16* thcn  = (u16*)(wsc + 25165824);     // [8][128][4096]
    u16* phcn  = (u16*)(wsc + 33554432);     // [8][128][4096] (later T2f)
    u16* gT    = (u16*)(wsc + 41943040);     // [8][4096][128]
    u16* zb    = (u16*)(wsc + 58720256);     // [8][4096][256]
    u16* g2p2  = (u16*)(wsc + 75497472);     // [8][128][4096] merged g2|p2
    float* attF  = (float*)(wsc + 83886080); // [8][128][128] (zero region start)
    float* SF    = (float*)(wsc + 84410368); // [8][128][128]
    float* meanS = (float*)(wsc + 84934656); // [8][256]
    u32*   maxU  = (u32*)  (wsc + 84942848); // [8][256]      (zero region end)
    float* ca  = (float*)(wsc + 85475328);   // [8][256]
    float* sain= (float*)(wsc + 85483520);   // [8][2][4096]
    u16* wsb   = (u16*)(wsc + 85745664);     // packed bf16 weights
    float* pb128 = (float*)(wsc + 86040576);
    u16* T2f   = phcn;                       // [8][2048][128] K-permuted fold

    u16* w_th = wsb + 0;
    u16* w_ph = wsb + 32768;
    u16* w_g  = wsb + 49152;
    u16* w_z  = wsb + 65536;
    u16* w_gp = wsb + 98304;
    u16* w_t2 = wsb + 114688;
    u16* w_zp = wsb + 131072;

    const long long sX0 = 524288, sCN = 524288, sAt = 16384;
    const long long sX  = 1048576;

    prep_tcast<<<dim3(4689), dim3(256), 0, stream>>>(x, xTb, x0, x0Tb,
        cnl_th_w, cnl_ph_w, cnl_g_w, cnl_W_w, pnl_g_w, pnl_ph_w, pnl_th_w, pnl_W_w,
        pnl_g_b, pnl_ph_b, attF, wsb, pb128);

    // level 1 (BM=128): th, ph, gT, g2p2 — B operands read once
    GJobs L1{}; L1.n = 4;
    L1.j[0] = mkjob(w_th, xTb, thcn, 0, cnl_th_b, 0, sX, sCN,
                    256, 256, 4096, 256, 1, 0, 1, 32, 1);
    L1.j[1] = mkjob(w_ph, x0Tb, phcn, 0, cnl_ph_b, 0, sX0, sCN,
                    128, 128, 4096, 128, 1, 0, 1, 32, 1);
    L1.j[2] = mkjob(x0Tb, w_g, gT, 0, cnl_g_b, sX0, 0, sX0,
                    128, 128, 128, 128, 1, 0, 0, 1, 32);
    L1.j[3] = mkjob(w_gp, x0Tb, g2p2, 0, pb128, 0, sX0, sCN,
                    128, 128, 4096, 128, 1, 0, 1, 32, 1);
    mfma_multi<128, 128><<<dim3(1024), dim3(256), 0, stream>>>(L1);

    // split-K: att + S
    GJobs SK{}; SK.n = 2;
    SK.j[0] = mkjob(thcn, phcn, 0, attF, 0, sCN, sCN, sAt,
                    4096, 4096, 128, 4096, 16, 1, 0, 1, 2);
    SK.j[1] = mkjob(g2p2, g2p2 + 262144, 0, SF, 0, sCN, sCN, sAt,
                    2048, 2048, 128, 2048, 8, 1, 0, 1, 2);
    mfma_multi<64, 128><<<dim3(384), dim3(256), 0, stream>>>(SK);

    // fused yT -> z_cnl -> t2
    y3<<<dim3(1, 64, 8), dim3(256), 0, stream>>>(gT, attF, w_z, xTb, w_t2, zb, T2f,
        cnl_W_b, cnl_bn_g, cnl_bn_b, cnl_bn_m, cnl_bn_v, pnl_th_b);

    // fused Y -> z_pnl (+ mean/max)
    p3<<<dim3(1, 32, 8), dim3(256), 0, stream>>>(T2f, SF, w_zp, zb, meanS, maxU,
        pnl_W_b, pnl_bn_g, pnl_bn_b, pnl_bn_m, pnl_bn_v);

    sa_ca<<<dim3(64, 8), dim3(256), 0, stream>>>(zb, meanS, maxU, ca_fc1, ca_fc2, ca, sain);
    fuse_conv<<<dim3(64, 4, 8), dim3(256), 0, stream>>>(zb, ca, sain, sa_w, x, fw, out);
}